// Round 5
// baseline (382.485 us; speedup 1.0000x reference)
//
#include <hip/hip_runtime.h>
#include <stdint.h>

typedef unsigned short u16;
typedef __attribute__((ext_vector_type(8))) __bf16 bf16x8;
typedef __attribute__((ext_vector_type(4))) float f32x4;
typedef __attribute__((ext_vector_type(4))) unsigned short u16x4;

#define MFMA16(a,b,c) __builtin_amdgcn_mfma_f32_16x16x32_bf16(a,b,c,0,0,0)

// f32 -> bf16 bits, round-to-nearest-even
static __device__ __forceinline__ u16 f2b(float f){
  uint32_t u = __float_as_uint(f);
  u += 0x7fffu + ((u >> 16) & 1u);
  return (u16)(u >> 16);
}

static __device__ __forceinline__ void gload_lds16(const void* g, void* l){
  __builtin_amdgcn_global_load_lds(
      (__attribute__((address_space(1))) void*)(uintptr_t)g,
      (__attribute__((address_space(3))) void*)(uintptr_t)l,
      16, 0, 0);
}

// ---------------- fp32 -> bf16 elementwise ----------------
__global__ __launch_bounds__(256) void cvt_bf16(const float* __restrict__ in,
                                                u16* __restrict__ out, int n){
  int i = (blockIdx.x * 256 + threadIdx.x) * 4;
  if (i >= n) return;
  float4 v = *(const float4*)(in + i);
  u16x4 o;
  o.x = f2b(v.x); o.y = f2b(v.y); o.z = f2b(v.z); o.w = f2b(v.w);
  *(u16x4*)(out + i) = o;
}

// ---------------- transpose+convert: in[K][N] f32 -> out[N][K] bf16 ----------------
__global__ __launch_bounds__(256) void transpose_cvt(const float* __restrict__ in,
                                                     u16* __restrict__ out,
                                                     int K, int N){
  __shared__ float tile[32][33];
  const int nb = blockIdx.x * 32, kb = blockIdx.y * 32;
  const int tx = threadIdx.x, ty = threadIdx.y; // (32,8)
#pragma unroll
  for (int i = 0; i < 32; i += 8)
    tile[ty + i][tx] = in[(size_t)(kb + ty + i) * N + nb + tx];
  __syncthreads();
#pragma unroll
  for (int i = 0; i < 32; i += 8)
    out[(size_t)(nb + ty + i) * K + kb + tx] = f2b(tile[tx][ty + i]);
}

// ---------------- bf16 GEMM: C[M,N] = A[M,K] * Bt[N,K]^T + bias ----------------
// MODE 0: write fp32 C to Cout[M,N].
// MODE 1 (QKV): scatter q->[BH][S][64] bf16 (pre-scaled by 1/8*log2e),
//               k->[BH][S][64] bf16 (+present0 fp32),
//               v->[BH][64][S] bf16 transposed (+present1 fp32).
template<int MODE>
__global__ __launch_bounds__(256) void gemm_bf16(
    const u16* __restrict__ A, const u16* __restrict__ Bt,
    const float* __restrict__ bias, float* __restrict__ Cout,
    u16* __restrict__ q_bf, u16* __restrict__ k_bf, u16* __restrict__ vT_bf,
    int M, int N, int K)
{
  __shared__ u16 As[128 * 64];
  __shared__ u16 Bs[128 * 64];
  const int tid = threadIdx.x;
  const int w = tid >> 6, lane = tid & 63;
  const int l15 = lane & 15, lhi = lane >> 4;
  const int mBase = blockIdx.y * 128, nBase = blockIdx.x * 128;
  const int wr = w >> 1, wc = w & 1;

  f32x4 acc[4][4];
#pragma unroll
  for (int i = 0; i < 4; ++i)
#pragma unroll
    for (int j = 0; j < 4; ++j) acc[i][j] = f32x4{0.f, 0.f, 0.f, 0.f};

  const int nK = K >> 6;
  for (int kt = 0; kt < nK; ++kt){
    const int kb = kt << 6;
#pragma unroll
    for (int i = 0; i < 4; ++i){
      const int idx = i * 256 + tid;
      const int row = idx >> 3, c8 = idx & 7;
      gload_lds16(A  + (size_t)(mBase + row) * K + kb + c8 * 8,
                  As + (size_t)(i * 256 + w * 64) * 8);
      gload_lds16(Bt + (size_t)(nBase + row) * K + kb + c8 * 8,
                  Bs + (size_t)(i * 256 + w * 64) * 8);
    }
    __syncthreads();
#pragma unroll
    for (int kk = 0; kk < 2; ++kk){
      bf16x8 af[4], bb[4];
#pragma unroll
      for (int mi = 0; mi < 4; ++mi)
        af[mi] = *(const bf16x8*)&As[(wr * 64 + mi * 16 + l15) * 64 + kk * 32 + lhi * 8];
#pragma unroll
      for (int ni = 0; ni < 4; ++ni)
        bb[ni] = *(const bf16x8*)&Bs[(wc * 64 + ni * 16 + l15) * 64 + kk * 32 + lhi * 8];
#pragma unroll
      for (int mi = 0; mi < 4; ++mi)
#pragma unroll
        for (int ni = 0; ni < 4; ++ni)
          acc[mi][ni] = MFMA16(af[mi], bb[ni], acc[mi][ni]);
    }
    __syncthreads();
  }

  // epilogue
#pragma unroll
  for (int ni = 0; ni < 4; ++ni){
    const int col = nBase + wc * 64 + ni * 16 + l15;
    const float bv = bias[col];
#pragma unroll
    for (int mi = 0; mi < 4; ++mi){
#pragma unroll
      for (int r = 0; r < 4; ++r){
        const int row = mBase + wr * 64 + mi * 16 + lhi * 4 + r;
        const float v = acc[mi][ni][r] + bv;
        if (MODE == 0){
          Cout[(size_t)row * N + col] = v;
        } else {
          const int b = row >> 11, s = row & 2047;
          const int sec = col >> 10, nn = col & 1023;
          const int h = nn >> 6, d = nn & 63;
          const size_t bhsd = ((size_t)(b * 16 + h) * 2048 + s) * 64 + d;
          if (sec == 0){
            q_bf[bhsd] = f2b(v * 0.1803368801111204f);      // 1/8 * log2(e)
          } else if (sec == 1){
            k_bf[bhsd] = f2b(v);
            Cout[8388608 + bhsd] = v;                       // present[0] = k
          } else {
            vT_bf[((size_t)(b * 16 + h) * 64 + d) * 2048 + s] = f2b(v);
            Cout[16777216 + bhsd] = v;                      // present[1] = v
          }
        }
      }
    }
  }
}

// ---------------- causal flash attention ----------------
// grid (16, B*H). XCD-aware remap: all 16 q-tile blocks of one head land on
// ONE XCD (id%8), and the ~8 heads concurrently resident per XCD hold
// 8 x 512KB = 4MB of K/V = exactly the XCD L2 -> K/V loads become L2 hits.
// Each block processes q-tiles {31-bx, bx} (paired -> uniform 33 KV-iters).
// 4 waves/block, 16 q-rows/wave, KV blocks of 64. Swapped QK^T (mfma(K,Q)):
// lane holds 16 scores of ONE q-row -> softmax = in-lane + 2 shfl_xor.
// Defer-max (THR=8, exp2 domain) skips o-rescale most iterations.
__global__ __launch_bounds__(256) void attn_kern(
    const u16* __restrict__ q_bf, const u16* __restrict__ k_bf,
    const u16* __restrict__ vT_bf, u16* __restrict__ a_bf)
{
  const int S = 2048;
  // ---- XCD-locality block remap (bijective on [0,1024)) ----
  const int id = (int)blockIdx.x + 16 * (int)blockIdx.y;
  const int xcd = id & 7, slot = id >> 3;
  const int bh = xcd + 8 * (slot >> 4);   // all 16 blocks of bh share id%8
  const int bx = slot & 15;

  const int tid = threadIdx.x, w = tid >> 6, lane = tid & 63;
  const int l15 = lane & 15, lhi = lane >> 4;
  const u16* qp = q_bf + (size_t)bh * S * 64;
  const u16* kp = k_bf + (size_t)bh * S * 64;
  const u16* vp = vT_bf + (size_t)bh * 64 * S;
  const int b = bh >> 4, h = bh & 15;

  __shared__ u16 P_all[4][16 * 64];
  u16* P = &P_all[w][0];
  char* Pc = (char*)P;
  const int swz = (l15 & 7) << 4;

  for (int half = 0; half < 2; ++half){
    const int qt = (half == 0) ? (31 - bx) : bx;
    const int qr0 = qt * 64 + w * 16;

    const bf16x8 qf0 = *(const bf16x8*)&qp[(qr0 + l15) * 64 + lhi * 8];
    const bf16x8 qf1 = *(const bf16x8*)&qp[(qr0 + l15) * 64 + 32 + lhi * 8];

    f32x4 o[4];
#pragma unroll
    for (int df = 0; df < 4; ++df) o[df] = f32x4{0.f, 0.f, 0.f, 0.f};
    float m = -1e30f, l = 0.f;

    const int nIter = qt + 1;
    // preload K fragments for jb = 0
    bf16x8 kf[8];
#pragma unroll
    for (int nf = 0; nf < 4; ++nf){
      kf[2*nf]   = *(const bf16x8*)&kp[(nf * 16 + l15) * 64 + lhi * 8];
      kf[2*nf+1] = *(const bf16x8*)&kp[(nf * 16 + l15) * 64 + 32 + lhi * 8];
    }

    for (int it = 0; it < nIter; ++it){
      const int jb = it * 64;
      // QK^T swapped: s = K_tile * Q  ->  q = l15, kv = lhi*4 + r
      f32x4 s[4];
      __builtin_amdgcn_s_setprio(1);
#pragma unroll
      for (int nf = 0; nf < 4; ++nf){
        f32x4 z = {0.f, 0.f, 0.f, 0.f};
        z = MFMA16(kf[2*nf], qf0, z);
        z = MFMA16(kf[2*nf+1], qf1, z);
        s[nf] = z;
      }
      __builtin_amdgcn_s_setprio(0);
      // V fragments for this block (latency hides under softmax)
      bf16x8 vf[8];
#pragma unroll
      for (int kk = 0; kk < 2; ++kk)
#pragma unroll
        for (int df = 0; df < 4; ++df)
          vf[kk*4+df] = *(const bf16x8*)&vp[((size_t)(df * 16 + l15)) * S + jb + kk * 32 + lhi * 8];
      // load next-iteration K straight into kf (just consumed by QK MFMAs)
      const int jn = (it + 1 < nIter) ? (jb + 64) : 0;
#pragma unroll
      for (int nf = 0; nf < 4; ++nf){
        kf[2*nf]   = *(const bf16x8*)&kp[(jn + nf * 16 + l15) * 64 + lhi * 8];
        kf[2*nf+1] = *(const bf16x8*)&kp[(jn + nf * 16 + l15) * 64 + 32 + lhi * 8];
      }

      // causal mask only on the diagonal block (scores already in exp2 domain)
      if (it == nIter - 1){
        const int q = qr0 + l15;
#pragma unroll
        for (int nf = 0; nf < 4; ++nf)
#pragma unroll
          for (int r = 0; r < 4; ++r){
            const int kv = jb + nf * 16 + lhi * 4 + r;
            if (kv > q) s[nf][r] = -1e10f;
          }
      }
      // row max: 15 in-lane + 2 cross-lane
      float x = s[0][0];
#pragma unroll
      for (int nf = 0; nf < 4; ++nf)
#pragma unroll
        for (int r = 0; r < 4; ++r) x = fmaxf(x, s[nf][r]);
      x = fmaxf(x, __shfl_xor(x, 16));
      x = fmaxf(x, __shfl_xor(x, 32));
      // defer-max: rescale only when the running max grew by > 8 (2^8 headroom)
      if (__any(x - m > 8.0f)){
        const float mn = fmaxf(m, x);
        const float sc = exp2f(m - mn);
        m = mn;
        l *= sc;
        float scq[4];
#pragma unroll
        for (int r = 0; r < 4; ++r)
          scq[r] = __shfl(sc, (lane & 48) | (lhi * 4 + r));
#pragma unroll
        for (int df = 0; df < 4; ++df)
#pragma unroll
          for (int r = 0; r < 4; ++r) o[df][r] *= scq[r];
      }
      // p = exp2(s - m), row sum: in-lane + 2 cross-lane
      float rs = 0.f;
#pragma unroll
      for (int nf = 0; nf < 4; ++nf)
#pragma unroll
        for (int r = 0; r < 4; ++r){
          const float p = exp2f(s[nf][r] - m);
          s[nf][r] = p;
          rs += p;
        }
      rs += __shfl_xor(rs, 16);
      rs += __shfl_xor(rs, 32);
      l += rs;
      // P[q][kv] -> LDS, b64 writes, XOR-swizzled (bank-spread)
#pragma unroll
      for (int nf = 0; nf < 4; ++nf){
        u16x4 pk;
#pragma unroll
        for (int r = 0; r < 4; ++r) pk[r] = f2b(s[nf][r]);
        *(u16x4*)(Pc + ((l15 * 128 + nf * 32 + lhi * 8) ^ swz)) = pk;
      }
      // PV
      __builtin_amdgcn_s_setprio(1);
#pragma unroll
      for (int kk = 0; kk < 2; ++kk){
        const bf16x8 pa = *(const bf16x8*)(Pc + ((l15 * 128 + kk * 64 + lhi * 16) ^ swz));
#pragma unroll
        for (int df = 0; df < 4; ++df)
          o[df] = MFMA16(pa, vf[kk*4+df], o[df]);
      }
      __builtin_amdgcn_s_setprio(0);
    }
    // finalize: broadcast 1/l from softmax lanes, store a[b][s][h*64+d]
    const float linv = 1.0f / l;
    float lr[4];
#pragma unroll
    for (int r = 0; r < 4; ++r)
      lr[r] = __shfl(linv, (lane & 48) | (lhi * 4 + r));
#pragma unroll
    for (int r = 0; r < 4; ++r){
      const int qrow = qr0 + lhi * 4 + r;
#pragma unroll
      for (int df = 0; df < 4; ++df)
        a_bf[((size_t)b * 2048 + qrow) * 1024 + h * 64 + df * 16 + l15] = f2b(o[df][r] * lr[r]);
    }
  }
}

extern "C" void kernel_launch(void* const* d_in, const int* in_sizes, int n_in,
                              void* d_out, int out_size, void* d_ws, size_t ws_size,
                              hipStream_t stream)
{
  const float* x      = (const float*)d_in[0];
  const float* w_attn = (const float*)d_in[1];
  const float* b_attn = (const float*)d_in[2];
  const float* w_proj = (const float*)d_in[3];
  const float* b_proj = (const float*)d_in[4];
  float* out = (float*)d_out;
  char* ws = (char*)d_ws;
  const size_t MB = 1u << 20;
  u16* x_bf  = (u16*)(ws + 0);        // 16 MB, reused as a_bf after attention
  u16* wA_T  = (u16*)(ws + 16 * MB);  // 6 MB
  u16* wP_T  = (u16*)(ws + 22 * MB);  // 2 MB
  u16* q_bf  = (u16*)(ws + 24 * MB);  // 16 MB
  u16* k_bf  = (u16*)(ws + 40 * MB);  // 16 MB
  u16* vT_bf = (u16*)(ws + 56 * MB);  // 16 MB
  u16* a_bf  = x_bf;

  cvt_bf16<<<dim3(8192), dim3(256), 0, stream>>>(x, x_bf, 4 * 2048 * 1024);
  transpose_cvt<<<dim3(96, 32), dim3(32, 8), 0, stream>>>(w_attn, wA_T, 1024, 3072);
  transpose_cvt<<<dim3(32, 32), dim3(32, 8), 0, stream>>>(w_proj, wP_T, 1024, 1024);
  gemm_bf16<1><<<dim3(24, 64), dim3(256), 0, stream>>>(
      x_bf, wA_T, b_attn, out, q_bf, k_bf, vT_bf, 8192, 3072, 1024);
  attn_kern<<<dim3(16, 64), dim3(256), 0, stream>>>(q_bf, k_bf, vT_bf, a_bf);
  gemm_bf16<0><<<dim3(8, 64), dim3(256), 0, stream>>>(
      a_bf, wP_T, b_proj, out, nullptr, nullptr, nullptr, 8192, 1024, 1024);
}

// Round 6
// 278.173 us; speedup vs baseline: 1.3750x; 1.3750x over previous
//
#include <hip/hip_runtime.h>
#include <stdint.h>

typedef unsigned short u16;
typedef __attribute__((ext_vector_type(8))) __bf16 bf16x8;
typedef __attribute__((ext_vector_type(4))) float f32x4;
typedef __attribute__((ext_vector_type(4))) unsigned short u16x4;

#define MFMA16(a,b,c) __builtin_amdgcn_mfma_f32_16x16x32_bf16(a,b,c,0,0,0)

// f32 -> bf16 bits, round-to-nearest-even
static __device__ __forceinline__ u16 f2b(float f){
  uint32_t u = __float_as_uint(f);
  u += 0x7fffu + ((u >> 16) & 1u);
  return (u16)(u >> 16);
}

static __device__ __forceinline__ void gload_lds16(const void* g, void* l){
  __builtin_amdgcn_global_load_lds(
      (__attribute__((address_space(1))) void*)(uintptr_t)g,
      (__attribute__((address_space(3))) void*)(uintptr_t)l,
      16, 0, 0);
}

// ---------------- fp32 -> bf16 elementwise ----------------
__global__ __launch_bounds__(256) void cvt_bf16(const float* __restrict__ in,
                                                u16* __restrict__ out, int n){
  int i = (blockIdx.x * 256 + threadIdx.x) * 4;
  if (i >= n) return;
  float4 v = *(const float4*)(in + i);
  u16x4 o;
  o.x = f2b(v.x); o.y = f2b(v.y); o.z = f2b(v.z); o.w = f2b(v.w);
  *(u16x4*)(out + i) = o;
}

// ---------------- transpose+convert: in[K][N] f32 -> out[N][K] bf16 ----------------
__global__ __launch_bounds__(256) void transpose_cvt(const float* __restrict__ in,
                                                     u16* __restrict__ out,
                                                     int K, int N){
  __shared__ float tile[32][33];
  const int nb = blockIdx.x * 32, kb = blockIdx.y * 32;
  const int tx = threadIdx.x, ty = threadIdx.y; // (32,8)
#pragma unroll
  for (int i = 0; i < 32; i += 8)
    tile[ty + i][tx] = in[(size_t)(kb + ty + i) * N + nb + tx];
  __syncthreads();
#pragma unroll
  for (int i = 0; i < 32; i += 8)
    out[(size_t)(nb + ty + i) * K + kb + tx] = f2b(tile[tx][ty + i]);
}

// ---------------- bf16 GEMM: C[M,N] = A[M,K] * Bt[N,K]^T + bias ----------------
// MODE 0: write fp32 C to Cout[M,N].
// MODE 1 (QKV): scatter q->[BH][S][64] bf16 (pre-scaled by 1/8*log2e),
//               k->[BH][S][64] bf16 (+present0 fp32),
//               v->[BH][64][S] bf16 transposed (+present1 fp32).
template<int MODE>
__global__ __launch_bounds__(256) void gemm_bf16(
    const u16* __restrict__ A, const u16* __restrict__ Bt,
    const float* __restrict__ bias, float* __restrict__ Cout,
    u16* __restrict__ q_bf, u16* __restrict__ k_bf, u16* __restrict__ vT_bf,
    int M, int N, int K)
{
  __shared__ u16 As[128 * 64];
  __shared__ u16 Bs[128 * 64];
  const int tid = threadIdx.x;
  const int w = tid >> 6, lane = tid & 63;
  const int l15 = lane & 15, lhi = lane >> 4;
  const int mBase = blockIdx.y * 128, nBase = blockIdx.x * 128;
  const int wr = w >> 1, wc = w & 1;

  f32x4 acc[4][4];
#pragma unroll
  for (int i = 0; i < 4; ++i)
#pragma unroll
    for (int j = 0; j < 4; ++j) acc[i][j] = f32x4{0.f, 0.f, 0.f, 0.f};

  const int nK = K >> 6;
  for (int kt = 0; kt < nK; ++kt){
    const int kb = kt << 6;
#pragma unroll
    for (int i = 0; i < 4; ++i){
      const int idx = i * 256 + tid;
      const int row = idx >> 3, c8 = idx & 7;
      gload_lds16(A  + (size_t)(mBase + row) * K + kb + c8 * 8,
                  As + (size_t)(i * 256 + w * 64) * 8);
      gload_lds16(Bt + (size_t)(nBase + row) * K + kb + c8 * 8,
                  Bs + (size_t)(i * 256 + w * 64) * 8);
    }
    __syncthreads();
#pragma unroll
    for (int kk = 0; kk < 2; ++kk){
      bf16x8 af[4], bb[4];
#pragma unroll
      for (int mi = 0; mi < 4; ++mi)
        af[mi] = *(const bf16x8*)&As[(wr * 64 + mi * 16 + l15) * 64 + kk * 32 + lhi * 8];
#pragma unroll
      for (int ni = 0; ni < 4; ++ni)
        bb[ni] = *(const bf16x8*)&Bs[(wc * 64 + ni * 16 + l15) * 64 + kk * 32 + lhi * 8];
#pragma unroll
      for (int mi = 0; mi < 4; ++mi)
#pragma unroll
        for (int ni = 0; ni < 4; ++ni)
          acc[mi][ni] = MFMA16(af[mi], bb[ni], acc[mi][ni]);
    }
    __syncthreads();
  }

  // epilogue
#pragma unroll
  for (int ni = 0; ni < 4; ++ni){
    const int col = nBase + wc * 64 + ni * 16 + l15;
    const float bv = bias[col];
#pragma unroll
    for (int mi = 0; mi < 4; ++mi){
#pragma unroll
      for (int r = 0; r < 4; ++r){
        const int row = mBase + wr * 64 + mi * 16 + lhi * 4 + r;
        const float v = acc[mi][ni][r] + bv;
        if (MODE == 0){
          Cout[(size_t)row * N + col] = v;
        } else {
          const int b = row >> 11, s = row & 2047;
          const int sec = col >> 10, nn = col & 1023;
          const int h = nn >> 6, d = nn & 63;
          const size_t bhsd = ((size_t)(b * 16 + h) * 2048 + s) * 64 + d;
          if (sec == 0){
            q_bf[bhsd] = f2b(v * 0.1803368801111204f);      // 1/8 * log2(e)
          } else if (sec == 1){
            k_bf[bhsd] = f2b(v);
            Cout[8388608 + bhsd] = v;                       // present[0] = k
          } else {
            vT_bf[((size_t)(b * 16 + h) * 64 + d) * 2048 + s] = f2b(v);
            Cout[16777216 + bhsd] = v;                      // present[1] = v
          }
        }
      }
    }
  }
}

// ---------------- causal flash attention ----------------
// grid (8, 64) -> 512 blocks. Each block: 128-row q-tile pair {15-bx, bx}
// (uniform ~33 iters). 4 waves/block, 32 q-rows/wave (2 x 16-row groups),
// KV blocks of 64 -> each 16KB K/V fetch feeds 32 MFMAs (2x intensity of
// 16-row waves; the cache-port is the bottleneck). XCD remap keeps all
// blocks of one head on one XCD (K/V stays L2-resident).
// Swapped QK^T (mfma(K,Q)): lane holds 16 scores of ONE q-row -> softmax =
// in-lane + 2 shfl_xor. Defer-max (THR=8, exp2 domain).
__global__ __launch_bounds__(256, 2) void attn_kern(
    const u16* __restrict__ q_bf, const u16* __restrict__ k_bf,
    const u16* __restrict__ vT_bf, u16* __restrict__ a_bf)
{
  const int S = 2048;
  // ---- XCD-locality block remap (bijective on [0,512)) ----
  const int id = (int)blockIdx.x + 8 * (int)blockIdx.y;
  const int xcd = id & 7, j = id >> 3;
  const int bh = xcd + 8 * (j & 7);   // all 8 blocks of bh share id%8
  const int bx = j >> 3;              // 0..7

  const int tid = threadIdx.x, w = tid >> 6, lane = tid & 63;
  const int l15 = lane & 15, lhi = lane >> 4;
  const u16* qp = q_bf + (size_t)bh * S * 64;
  const u16* kp = k_bf + (size_t)bh * S * 64;
  const u16* vp = vT_bf + (size_t)bh * 64 * S;
  const int b = bh >> 4, h = bh & 15;

  __shared__ u16 P_all[4][32 * 64];
  char* Pc = (char*)&P_all[w][0];
  const int swz = (l15 & 7) << 4;

  for (int half = 0; half < 2; ++half){
    const int qt = (half == 0) ? (15 - bx) : bx;
    const int qr0 = qt * 128 + w * 32;

    bf16x8 qf[2][2];
#pragma unroll
    for (int g = 0; g < 2; ++g){
      qf[g][0] = *(const bf16x8*)&qp[(qr0 + g * 16 + l15) * 64 + lhi * 8];
      qf[g][1] = *(const bf16x8*)&qp[(qr0 + g * 16 + l15) * 64 + 32 + lhi * 8];
    }

    f32x4 o[2][4];
#pragma unroll
    for (int g = 0; g < 2; ++g)
#pragma unroll
      for (int df = 0; df < 4; ++df) o[g][df] = f32x4{0.f, 0.f, 0.f, 0.f};
    float m[2] = {-1e30f, -1e30f}, l[2] = {0.f, 0.f};

    const int nIter = 2 * qt + 1 + (w >> 1);
    // preload K fragments for jb = 0
    bf16x8 kf[8];
#pragma unroll
    for (int nf = 0; nf < 4; ++nf){
      kf[2*nf]   = *(const bf16x8*)&kp[(nf * 16 + l15) * 64 + lhi * 8];
      kf[2*nf+1] = *(const bf16x8*)&kp[(nf * 16 + l15) * 64 + 32 + lhi * 8];
    }

    for (int it = 0; it < nIter; ++it){
      const int jb = it * 64;
      // V fragments first (latency hides under QK + softmax; waits stay counted)
      bf16x8 vf[8];
#pragma unroll
      for (int kk = 0; kk < 2; ++kk)
#pragma unroll
        for (int df = 0; df < 4; ++df)
          vf[kk*4+df] = *(const bf16x8*)&vp[((size_t)(df * 16 + l15)) * S + jb + kk * 32 + lhi * 8];
      // QK^T swapped: s = K_tile * Q  ->  q-col = l15, kv = nf*16 + lhi*4 + r
      f32x4 s[2][4];
      __builtin_amdgcn_s_setprio(1);
#pragma unroll
      for (int g = 0; g < 2; ++g)
#pragma unroll
        for (int nf = 0; nf < 4; ++nf){
          f32x4 z = {0.f, 0.f, 0.f, 0.f};
          z = MFMA16(kf[2*nf], qf[g][0], z);
          z = MFMA16(kf[2*nf+1], qf[g][1], z);
          s[g][nf] = z;
        }
      __builtin_amdgcn_s_setprio(0);
      // load next-iteration K straight into kf (just consumed by QK MFMAs)
      const int jn = (it + 1 < nIter) ? (jb + 64) : 0;
#pragma unroll
      for (int nf = 0; nf < 4; ++nf){
        kf[2*nf]   = *(const bf16x8*)&kp[(jn + nf * 16 + l15) * 64 + lhi * 8];
        kf[2*nf+1] = *(const bf16x8*)&kp[(jn + nf * 16 + l15) * 64 + 32 + lhi * 8];
      }

      // causal mask only on the last iteration of this wave
      if (it == nIter - 1){
#pragma unroll
        for (int g = 0; g < 2; ++g){
          const int q = qr0 + g * 16 + l15;
#pragma unroll
          for (int nf = 0; nf < 4; ++nf)
#pragma unroll
            for (int r = 0; r < 4; ++r){
              const int kv = jb + nf * 16 + lhi * 4 + r;
              if (kv > q) s[g][nf][r] = -1e10f;
            }
        }
      }
#pragma unroll
      for (int g = 0; g < 2; ++g){
        // row max: 15 in-lane + 2 cross-lane
        float x = s[g][0][0];
#pragma unroll
        for (int nf = 0; nf < 4; ++nf)
#pragma unroll
          for (int r = 0; r < 4; ++r) x = fmaxf(x, s[g][nf][r]);
        x = fmaxf(x, __shfl_xor(x, 16));
        x = fmaxf(x, __shfl_xor(x, 32));
        // defer-max: rescale only when running max grew by > 8 (2^8 headroom)
        if (__any(x - m[g] > 8.0f)){
          const float mn = fmaxf(m[g], x);
          const float sc = exp2f(m[g] - mn);
          m[g] = mn;
          l[g] *= sc;
          float scq[4];
#pragma unroll
          for (int r = 0; r < 4; ++r)
            scq[r] = __shfl(sc, (lane & 48) | (lhi * 4 + r));
#pragma unroll
          for (int df = 0; df < 4; ++df)
#pragma unroll
            for (int r = 0; r < 4; ++r) o[g][df][r] *= scq[r];
        }
        // p = exp2(s - m), row sum: in-lane + 2 cross-lane
        float rs = 0.f;
#pragma unroll
        for (int nf = 0; nf < 4; ++nf)
#pragma unroll
          for (int r = 0; r < 4; ++r){
            const float p = exp2f(s[g][nf][r] - m[g]);
            s[g][nf][r] = p;
            rs += p;
          }
        rs += __shfl_xor(rs, 16);
        rs += __shfl_xor(rs, 32);
        l[g] += rs;
        // P[q][kv] -> LDS, b64 writes, XOR-swizzled
#pragma unroll
        for (int nf = 0; nf < 4; ++nf){
          u16x4 pk;
#pragma unroll
          for (int r = 0; r < 4; ++r) pk[r] = f2b(s[g][nf][r]);
          *(u16x4*)(Pc + (((g * 16 + l15) * 128 + nf * 32 + lhi * 8) ^ swz)) = pk;
        }
      }
      // PV for both groups
      __builtin_amdgcn_s_setprio(1);
#pragma unroll
      for (int g = 0; g < 2; ++g)
#pragma unroll
        for (int kk = 0; kk < 2; ++kk){
          const bf16x8 pa = *(const bf16x8*)(Pc + (((g * 16 + l15) * 128 + kk * 64 + lhi * 16) ^ swz));
#pragma unroll
          for (int df = 0; df < 4; ++df)
            o[g][df] = MFMA16(pa, vf[kk*4+df], o[g][df]);
        }
      __builtin_amdgcn_s_setprio(0);
    }
    // finalize: broadcast 1/l per group, store a[b][s][h*64+d]
#pragma unroll
    for (int g = 0; g < 2; ++g){
      const float linv = 1.0f / l[g];
      float lr[4];
#pragma unroll
      for (int r = 0; r < 4; ++r)
        lr[r] = __shfl(linv, (lane & 48) | (lhi * 4 + r));
#pragma unroll
      for (int r = 0; r < 4; ++r){
        const int qrow = qr0 + g * 16 + lhi * 4 + r;
#pragma unroll
        for (int df = 0; df < 4; ++df)
          a_bf[((size_t)b * 2048 + qrow) * 1024 + h * 64 + df * 16 + l15] = f2b(o[g][df][r] * lr[r]);
      }
    }
  }
}

extern "C" void kernel_launch(void* const* d_in, const int* in_sizes, int n_in,
                              void* d_out, int out_size, void* d_ws, size_t ws_size,
                              hipStream_t stream)
{
  const float* x      = (const float*)d_in[0];
  const float* w_attn = (const float*)d_in[1];
  const float* b_attn = (const float*)d_in[2];
  const float* w_proj = (const float*)d_in[3];
  const float* b_proj = (const float*)d_in[4];
  float* out = (float*)d_out;
  char* ws = (char*)d_ws;
  const size_t MB = 1u << 20;
  u16* x_bf  = (u16*)(ws + 0);        // 16 MB, reused as a_bf after attention
  u16* wA_T  = (u16*)(ws + 16 * MB);  // 6 MB
  u16* wP_T  = (u16*)(ws + 22 * MB);  // 2 MB
  u16* q_bf  = (u16*)(ws + 24 * MB);  // 16 MB
  u16* k_bf  = (u16*)(ws + 40 * MB);  // 16 MB
  u16* vT_bf = (u16*)(ws + 56 * MB);  // 16 MB
  u16* a_bf  = x_bf;

  cvt_bf16<<<dim3(8192), dim3(256), 0, stream>>>(x, x_bf, 4 * 2048 * 1024);
  transpose_cvt<<<dim3(96, 32), dim3(32, 8), 0, stream>>>(w_attn, wA_T, 1024, 3072);
  transpose_cvt<<<dim3(32, 32), dim3(32, 8), 0, stream>>>(w_proj, wP_T, 1024, 1024);
  gemm_bf16<1><<<dim3(24, 64), dim3(256), 0, stream>>>(
      x_bf, wA_T, b_attn, out, q_bf, k_bf, vT_bf, 8192, 3072, 1024);
  attn_kern<<<dim3(8, 64), dim3(256), 0, stream>>>(q_bf, k_bf, vT_bf, a_bf);
  gemm_bf16<0><<<dim3(8, 64), dim3(256), 0, stream>>>(
      a_bf, wP_T, b_proj, out, nullptr, nullptr, nullptr, 8192, 1024, 1024);
}